// Round 4
// baseline (364.475 us; speedup 1.0000x reference)
//
#include <hip/hip_runtime.h>
#include <hip/hip_bf16.h>

#define N_ROWS 4096
#define K_IN   8192
#define F_DIM  2048
#define GAMMA  (1.0f / 2048.0f)

typedef unsigned short u16;
typedef unsigned int   u32;
typedef unsigned char  u8;
typedef __attribute__((ext_vector_type(4))) int   i32x4;
typedef __attribute__((ext_vector_type(8))) int   i32x8;
typedef __attribute__((ext_vector_type(4))) float f32x4;
typedef __attribute__((ext_vector_type(2))) float f32x2;

// ---------------------------------------------------------------------------
// Fragment-major fp8 layout (validated R3: zero bank conflicts, gemm_xw fell
// below the 76us harness fills). A [R][K] matrix is stored as 2KB sub-tiles:
//   off(r,k) = (rt*(K/128) + kt)*2048 + h*1024 + (16*q + rr)*16 + b
//   rt=r>>4, rr=r&15, kt=k>>7, q=(k>>5)&3, h=(k>>4)&1, b=k&15
// = exactly the mfma_scale_f32_16x16x128 operand order: lane (16q+rr) reads
// lo 16B at lane*16 and hi 16B at lane*16+1024 within a sub-tile. Staging is
// a LINEAR copy; every frag ds_read_b128 is 64 lanes x 16B contiguous.
// ---------------------------------------------------------------------------

__device__ __forceinline__ u32 pk4_fp8(float a, float b, float c, float d) {
  u32 u = 0;
  u = __builtin_amdgcn_cvt_pk_fp8_f32(a, b, u, false);
  u = __builtin_amdgcn_cvt_pk_fp8_f32(c, d, u, true);
  return u;
}

__device__ __forceinline__ void async16(const void* g, void* l) {
  __builtin_amdgcn_global_load_lds(
      (const __attribute__((address_space(1))) void*)g,
      (__attribute__((address_space(3))) void*)l, 16, 0, 0);
}

// ---------------- conversion kernels ----------------

// xs fp32 [4096][8192] -> fp8 fragment-major. One block = one 2KB sub-tile
// (16 rows x 128 k). Reads coalesced, writes contiguous 2KB.
__global__ void convert_xs(const float* __restrict__ xs, u8* __restrict__ out) {
  __shared__ float t16[16][132];   // +4 pad: stagger banks for the read phase
  const int bid = blockIdx.x;      // 0..16383
  const int rt = bid >> 6, kt = bid & 63;
  const int tid = threadIdx.x;     // 256
  const float* src = xs + (size_t)rt * 16 * K_IN + kt * 128;
#pragma unroll
  for (int j = 0; j < 2; ++j) {
    int i = tid + j * 256;         // 0..511 float4s
    int row = i >> 5, c4 = (i & 31) << 2;
    float4 v = *(const float4*)(src + (size_t)row * K_IN + c4);
    t16[row][c4 + 0] = v.x; t16[row][c4 + 1] = v.y;
    t16[row][c4 + 2] = v.z; t16[row][c4 + 3] = v.w;
  }
  __syncthreads();
  const int cw = tid >> 1, part = tid & 1;
  const int h = cw >> 6, l = cw & 63, q = l >> 4, rr = l & 15;
  const float* p = &t16[rr][q * 32 + h * 16 + part * 8];
  u32 u0 = pk4_fp8(p[0], p[1], p[2], p[3]);
  u32 u1 = pk4_fp8(p[4], p[5], p[6], p[7]);
  uint2 st = {u0, u1};
  *(uint2*)(out + ((size_t)(rt * 64 + kt) << 11) + cw * 16 + part * 8) = st;
}

// W [K_IN, F_DIM] fp32 -> Wt fragment-major [F_DIM rows, K_IN], scaled x64
// (w~0.011 would be subnormal in e4m3; 2^-6 undone via MFMA B-scale 121).
// R4: pack through LDS so global writes are contiguous 16B (was 4B scattered
// within 2KB windows -> ~25% write-sector utilization).
__global__ void transpose_w(const float* __restrict__ W, u8* __restrict__ Wt) {
  __shared__ float tile[128][33];
  __shared__ u32 ob[1024];         // 4KB packed output (2 sub-tiles)
  int k0 = blockIdx.x * 128;       // over K_IN/128
  int f0 = blockIdx.y * 32;        // over F_DIM/32
  int tx = threadIdx.x, ty = threadIdx.y;   // (32, 8)
#pragma unroll
  for (int kk = 0; kk < 16; ++kk) {
    int k = kk * 8 + ty;
    tile[k][tx] = 64.0f * W[(size_t)(k0 + k) * F_DIM + f0 + tx];
  }
  __syncthreads();
#pragma unroll
  for (int ff = 0; ff < 4; ++ff) {
    int f = ff * 8 + ty;
    int kk = tx * 4;
    u32 p = pk4_fp8(tile[kk][f], tile[kk + 1][f], tile[kk + 2][f], tile[kk + 3][f]);
    int rtl = f >> 4, rr = f & 15;
    int q = kk >> 5, hh = (kk >> 4) & 1;
    ob[rtl * 512 + hh * 256 + (q * 16 + rr) * 4 + ((kk & 15) >> 2)] = p;
  }
  __syncthreads();
  const int t = ty * 32 + tx;      // 0..255
  const int kt = k0 >> 7, rt0 = f0 >> 4;
  uint4* dst = (uint4*)(Wt + ((size_t)((rt0 + (t >> 7)) * 64 + kt) << 11));
  dst[t & 127] = ((const uint4*)ob)[t];
}

// beta[i] = alpha[i]*(2*y[i]-1); out[0] = -sum(alpha); sq[] zeroed for the
// fused row-square accumulation in gemm_xw's epilogue.
__global__ void prep(const float* __restrict__ alphas, const int* __restrict__ ys,
                     float* __restrict__ beta, float* __restrict__ sq,
                     float* __restrict__ out) {
  __shared__ float red[1024];
  int t = threadIdx.x;
  float s = 0.f;
  for (int i = t; i < N_ROWS; i += 1024) {
    float a = alphas[i];
    beta[i] = a * (float)(2 * ys[i] - 1);
    sq[i] = 0.f;
    s += a;
  }
  red[t] = s;
  __syncthreads();
  for (int off = 512; off; off >>= 1) {
    if (t < off) red[t] += red[t + off];
    __syncthreads();
  }
  if (t == 0) out[0] = -red[0];
}

// ---- GEMM1: 256x128 tile, 512 thr, in-block split-K (2 halves x 4 waves),
// wave-tile 128x64. A single-buffered 32KB + B double-buffered 2x16KB per
// half = 128KB LDS. 2-phase loop {read af; barrier; stage kt+1 under MFMA;
// barrier}. grid=256 (1/CU), 2 waves/SIMD. Conflict-free frag reads.
// R4: + setprio around MFMA cluster; + fused row-sum-of-squares (replaces
// row_sq kernel; dequant of the SAME packed fp8 -> diag exactness kept).
__global__ __launch_bounds__(512, 2) void gemm_xw(const u8* __restrict__ A,
                                                  const u8* __restrict__ Bt,
                                                  u8* __restrict__ X,
                                                  float* __restrict__ sqp) {
  __shared__ __align__(16) u8 smem[131072];
  const int tid = threadIdx.x;
  // XCD-chunked swizzle: each XCD's 32 blocks cover 2 n-panels (2MB Wt ->
  // L2-resident) x all 16 m-tiles.
  const int wg = blockIdx.x;
  const int L = (wg & 7) * 32 + (wg >> 3);
  const int m0 = (L & 15) << 8;   // 16 m-tiles of 256
  const int n0 = (L >> 4) << 7;   // 16 n-tiles of 128

  const int lane = tid & 63;
  const int wave = tid >> 6;      // 0..7
  const int kh = wave >> 2;       // K-half: waves 0-3 -> k[0,4096), 4-7 -> rest
  const int w2 = wave & 3;
  const int wm = (w2 >> 1) << 7;  // 0 / 128
  const int wn = (w2 & 1) << 6;   // 0 / 64
  const int t = tid & 255;        // thread id within half

  u8* sA  = smem + kh * 65536;          // 32KB, single-buffered
  u8* sB0 = sA + 32768;                 // 16KB
  u8* sB1 = sB0 + 16384;                // 16KB

  const u8* pA = A  + (size_t)((m0 >> 4) + (t >> 7)) * 131072 + (t & 127) * 16;
  const u8* pB = Bt + (size_t)((n0 >> 4) + (t >> 7)) * 131072 + (t & 127) * 16;
  const int oT = t * 16;

  f32x4 acc[8][4];
  const f32x4 zero = {0.f, 0.f, 0.f, 0.f};
#pragma unroll
  for (int i = 0; i < 8; ++i)
#pragma unroll
    for (int j = 0; j < 4; ++j) acc[i][j] = zero;

#define STAGE_A(KT) { _Pragma("unroll") for (int j_ = 0; j_ < 8; ++j_) \
    async16(pA + (size_t)j_ * 262144 + (size_t)(KT) * 2048, sA + oT + j_ * 4096); }
#define STAGE_B(BUF, KT) { _Pragma("unroll") for (int j_ = 0; j_ < 4; ++j_) \
    async16(pB + (size_t)j_ * 262144 + (size_t)(KT) * 2048, (BUF) + oT + j_ * 4096); }
#define MFMA1(MT, NT, AF, BG) \
    acc[MT][NT] = __builtin_amdgcn_mfma_scale_f32_16x16x128_f8f6f4( \
        AF, BG, acc[MT][NT], 0, 0, 0, 127, 0, 121);

  const int kbase = kh * 32;      // this half's first k-tile (of 64)
  STAGE_A(kbase)
  STAGE_B(sB0, kbase)
  __syncthreads();                // vmcnt(0): tile kbase visible

  const int aB = lane * 16;
  const int sa0 = wm >> 4;        // A sub base: 0 or 8
  const int sb0i = wn >> 4;       // B sub base: 0 or 4

  for (int it = 0; it < 32; ++it) {
    const int kt = kbase + it;
    u8* sBc = (it & 1) ? sB1 : sB0;
    u8* sBn = (it & 1) ? sB0 : sB1;

    // phase 1: pull ALL A frags into regs (A is single-buffered)
    i32x8 af[8];
#pragma unroll
    for (int mt = 0; mt < 8; ++mt) {
      const u8* b_ = sA + (sa0 + mt) * 2048 + aB;
      i32x4 lo = *(const i32x4*)(b_);
      i32x4 hi = *(const i32x4*)(b_ + 1024);
      af[mt] = (i32x8){lo[0], lo[1], lo[2], lo[3], hi[0], hi[1], hi[2], hi[3]};
    }
    __syncthreads();              // af in regs; A + B[cur] consumed-enough

    // phase 2: stage kt+1 (A and B-next) under the MFMA cluster
    if (it < 31) { STAGE_A(kt + 1) STAGE_B(sBn, kt + 1) }
    __builtin_amdgcn_s_setprio(1);
#pragma unroll
    for (int nt = 0; nt < 4; ++nt) {
      const u8* b_ = sBc + (sb0i + nt) * 2048 + aB;
      i32x4 lo = *(const i32x4*)(b_);
      i32x4 hi = *(const i32x4*)(b_ + 1024);
      i32x8 bg = (i32x8){lo[0], lo[1], lo[2], lo[3], hi[0], hi[1], hi[2], hi[3]};
      MFMA1(0, nt, af[0], bg) MFMA1(1, nt, af[1], bg)
      MFMA1(2, nt, af[2], bg) MFMA1(3, nt, af[3], bg)
      MFMA1(4, nt, af[4], bg) MFMA1(5, nt, af[5], bg)
      MFMA1(6, nt, af[6], bg) MFMA1(7, nt, af[7], bg)
    }
    __builtin_amdgcn_s_setprio(0);
    __syncthreads();              // vmcnt(0): kt+1 landed (covered by MFMAs)
  }
#undef STAGE_A
#undef STAGE_B
#undef MFMA1

  // merge K-halves through LDS, quantize + store (fragment-major X), and
  // accumulate row sums of dequantized squares into sq (replaces row_sq).
  __syncthreads();
  float* red = (float*)smem;      // 256 thr x 32 vec4 = 128KB
  if (kh == 1) {
#pragma unroll
    for (int mt = 0; mt < 8; ++mt)
#pragma unroll
      for (int nt = 0; nt < 4; ++nt)
        *(f32x4*)(red + ((size_t)t * 32 + mt * 4 + nt) * 4) = acc[mt][nt];
  }
  __syncthreads();
  if (kh == 0) {
    const int q = lane >> 4, r = lane & 15;
    const int qq0 = wn >> 5;      // 0 or 2
#pragma unroll
    for (int mt = 0; mt < 8; ++mt) {
      float rs[4] = {0.f, 0.f, 0.f, 0.f};
#pragma unroll
      for (int nt = 0; nt < 4; ++nt) {
        f32x4 v = acc[mt][nt] + *(const f32x4*)(red + ((size_t)t * 32 + mt * 4 + nt) * 4);
        u32 pk = pk4_fp8(v[0], v[1], v[2], v[3]);
        f32x2 lo = __builtin_amdgcn_cvt_pk_f32_fp8(pk, false);
        f32x2 hi = __builtin_amdgcn_cvt_pk_f32_fp8(pk, true);
        rs[0] += lo[0] * lo[0]; rs[1] += lo[1] * lo[1];
        rs[2] += hi[0] * hi[0]; rs[3] += hi[1] * hi[1];
        const int rt = (m0 >> 4) + (wm >> 4) + mt;
        const int qq = qq0 + (nt >> 1);
        const int hh = nt & 1;
        u8* dst = X + (size_t)rt * 32768 + (size_t)(n0 >> 7) * 2048 + hh * 1024 + r;
        dst[(qq * 16 + ((q << 2) + 0)) * 16] = (u8)(pk & 0xff);
        dst[(qq * 16 + ((q << 2) + 1)) * 16] = (u8)((pk >> 8) & 0xff);
        dst[(qq * 16 + ((q << 2) + 2)) * 16] = (u8)((pk >> 16) & 0xff);
        dst[(qq * 16 + ((q << 2) + 3)) * 16] = (u8)(pk >> 24);
      }
      // reduce each row-slice over the 16-lane r-group, one atomic per row
#pragma unroll
      for (int e = 0; e < 4; ++e) {
        float s = rs[e];
        s += __shfl_xor(s, 1); s += __shfl_xor(s, 2);
        s += __shfl_xor(s, 4); s += __shfl_xor(s, 8);
        if (r == 0) atomicAdd(sqp + m0 + wm + (mt << 4) + (q << 2) + e, s);
      }
    }
  }
}

// ------- gram GEMM core on fragment-major X: 128x128 tile -------
// R4: pipelined — double-buffered A and B (64KB), stage kt+1 issued BEFORE
// the frag reads + MFMA cluster, ONE barrier per K-step (drains vmcnt).
__device__ __forceinline__ void gemm_tile_x(const u8* __restrict__ X, int m0, int n0,
                                            u8 (*sA)[16384], u8 (*sB)[16384],
                                            int tid, f32x4 acc[4][4]) {
  const int lane = tid & 63;
  const int wave = tid >> 6;
  const f32x4 zero = {0.f, 0.f, 0.f, 0.f};
#pragma unroll
  for (int mt = 0; mt < 4; ++mt)
#pragma unroll
    for (int nt = 0; nt < 4; ++nt) acc[mt][nt] = zero;

  // staging (linear copy; X sub-stride = 16*2048 = 32768, 16 k-tiles)
  const u8* pA = X + (size_t)((m0 >> 4) + (tid >> 7)) * 32768 + (tid & 127) * 16;
  const u8* pB = X + (size_t)((n0 >> 4) + (tid >> 7)) * 32768 + (tid & 127) * 16;
  const int oT = tid * 16;
  const int aB = lane * 16;
  const int sa0 = (wave >> 1) * 4, sb0 = (wave & 1) * 4;

#define STG(KT, BUF) { _Pragma("unroll") for (int j_ = 0; j_ < 4; ++j_) { \
    async16(pA + (size_t)j_ * 65536 + (size_t)(KT) * 2048, sA[BUF] + oT + j_ * 4096); \
    async16(pB + (size_t)j_ * 65536 + (size_t)(KT) * 2048, sB[BUF] + oT + j_ * 4096); } }

  STG(0, 0)
  __syncthreads();                // tile 0 visible

  for (int kt = 0; kt < 16; ++kt) {
    const int cur = kt & 1, nxt = cur ^ 1;
    if (kt < 15) STG(kt + 1, nxt)   // issue early: latency hidden under MFMA

    i32x8 af[4], bg[4];
#pragma unroll
    for (int mt = 0; mt < 4; ++mt) {
      const u8* b_ = sA[cur] + (sa0 + mt) * 2048 + aB;
      i32x4 lo = *(const i32x4*)(b_);
      i32x4 hi = *(const i32x4*)(b_ + 1024);
      af[mt] = (i32x8){lo[0], lo[1], lo[2], lo[3], hi[0], hi[1], hi[2], hi[3]};
    }
#pragma unroll
    for (int nt = 0; nt < 4; ++nt) {
      const u8* b_ = sB[cur] + (sb0 + nt) * 2048 + aB;
      i32x4 lo = *(const i32x4*)(b_);
      i32x4 hi = *(const i32x4*)(b_ + 1024);
      bg[nt] = (i32x8){lo[0], lo[1], lo[2], lo[3], hi[0], hi[1], hi[2], hi[3]};
    }
    __builtin_amdgcn_s_setprio(1);
#pragma unroll
    for (int mt = 0; mt < 4; ++mt)
#pragma unroll
      for (int nt = 0; nt < 4; ++nt)
        acc[mt][nt] = __builtin_amdgcn_mfma_scale_f32_16x16x128_f8f6f4(
            af[mt], bg[nt], acc[mt][nt], 0, 0, 0, 127, 0, 127);
    __builtin_amdgcn_s_setprio(0);
    __syncthreads();              // vmcnt(0): kt+1 landed; cur reads done
  }
#undef STG
}

// GEMM2 (triangular) + fused RBF epilogue + reduction
__global__ __launch_bounds__(256, 2) void gemm_kern(const u8* __restrict__ X,
                                                    const float* __restrict__ sq,
                                                    const float* __restrict__ beta,
                                                    float* __restrict__ out) {
  __shared__ __align__(16) u8 sA[2][16384];
  __shared__ __align__(16) u8 sB[2][16384];
  const int tid = threadIdx.x;
  int bid = blockIdx.x;
  int ib = 0;
  while (bid >= 32 - ib) { bid -= 32 - ib; ++ib; }
  const int jb = ib + bid;
  const int m0 = ib << 7;
  const int n0 = jb << 7;

  f32x4 acc[4][4];
  gemm_tile_x(X, m0, n0, sA, sB, tid, acc);

  const int lane = tid & 63;
  const int q = lane >> 4;
  const int r = lane & 15;
  const int wave = tid >> 6;
  const int wm = (wave >> 1) << 6;
  const int wn = (wave & 1) << 6;

  float sqj[4], bj[4];
#pragma unroll
  for (int nt = 0; nt < 4; ++nt) {
    int j = n0 + wn + (nt << 4) + r;
    sqj[nt] = sq[j];
    bj[nt] = beta[j];
  }
  float local = 0.f;
#pragma unroll
  for (int mt = 0; mt < 4; ++mt) {
#pragma unroll
    for (int e = 0; e < 4; ++e) {
      int i = m0 + wm + (mt << 4) + (q << 2) + e;
      float sqi = sq[i];
      float bi = beta[i];
#pragma unroll
      for (int nt = 0; nt < 4; ++nt) {
        float d2 = fmaxf(sqi + sqj[nt] - 2.f * acc[mt][nt][e], 0.f);
        local += bi * bj[nt] * __expf(-GAMMA * d2);
      }
    }
  }
  // diag blocks once (x0.5 for the 0.5*quad form), off-diag twice (x1.0)
  local *= (ib == jb) ? 0.5f : 1.0f;
#pragma unroll
  for (int off = 32; off; off >>= 1) local += __shfl_down(local, off);
  if (lane == 0) atomicAdd(out, local);
}

// ---------------- launch ----------------

extern "C" void kernel_launch(void* const* d_in, const int* in_sizes, int n_in,
                              void* d_out, int out_size, void* d_ws, size_t ws_size,
                              hipStream_t stream) {
  const float* xs = (const float*)d_in[0];
  const float* W = (const float*)d_in[1];
  const int* ys = (const int*)d_in[2];
  const float* alphas = (const float*)d_in[3];
  float* out = (float*)d_out;

  char* ws = (char*)d_ws;
  u8* xs_f8 = (u8*)ws;                        //  32 MB: [4096, 8192] fp8 frag-major
  u8* Wt_f8 = (u8*)(ws + 33554432);           //  16 MB: [2048, 8192] fp8 frag-major (x64)
  u8* X_f8  = (u8*)(ws + 50331648);           //   8 MB: [4096, 2048] fp8 frag-major
  float* sq   = (float*)(ws + 58720256);      //  16 KB
  float* beta = (float*)(ws + 58736640);      //  16 KB

  convert_xs<<<16384, 256, 0, stream>>>(xs, xs_f8);
  dim3 tb(32, 8);
  dim3 tg(K_IN / 128, F_DIM / 32);
  transpose_w<<<tg, tb, 0, stream>>>(W, Wt_f8);
  prep<<<1, 1024, 0, stream>>>(alphas, ys, beta, sq, out);

  gemm_xw<<<256, 512, 0, stream>>>(xs_f8, Wt_f8, X_f8, sq);
  gemm_kern<<<528, 256, 0, stream>>>(X_f8, sq, beta, out);
}